// Round 3
// baseline (594.259 us; speedup 1.0000x reference)
//
#include <hip/hip_runtime.h>
#include <cstdint>
#include <cstddef>

// Problem constants
#define TOKENS 2048
#define DM 1024
#define DFF 2048
#define HC 4096     // 2*DFF
#define NE 16
#define PADROWS 2560   // padded slot capacity (2048 + 16*15 pad + slack)

typedef __bf16 bf16x8 __attribute__((ext_vector_type(8)));
typedef float floatx4 __attribute__((ext_vector_type(4)));

static __device__ __forceinline__ unsigned short f2bf(float f) {
    union { float f; unsigned int u; } v; v.f = f;
    unsigned int r = v.u + 0x7fffu + ((v.u >> 16) & 1u);  // RNE
    return (unsigned short)(r >> 16);
}

union BF8 { bf16x8 v; unsigned short u[8]; };

// ---------------- gating: logits (fp64 accum), softmax, argmax — no atomics --
__global__ __launch_bounds__(256) void moe_gating(
    const float* __restrict__ x, const float* __restrict__ Wga, const float* __restrict__ bga,
    const float* __restrict__ Wgb, const float* __restrict__ bgb,
    float* __restrict__ probsA, float* __restrict__ probsB, int* __restrict__ e_idx)
{
    int wv = threadIdx.x >> 6, lane = threadIdx.x & 63;
    int t = blockIdx.x * 4 + wv;
    const float* xr = x + (size_t)t * DM;
    double aA[4] = {0.,0.,0.,0.}, aB[4] = {0.,0.,0.,0.};
    for (int k = lane; k < DM; k += 64) {
        double xv = (double)xr[k];
        float4 wa = *(const float4*)(Wga + k * 4);
        float4 wb = *(const float4*)(Wgb + k * 4);
        aA[0] += xv * wa.x; aA[1] += xv * wa.y; aA[2] += xv * wa.z; aA[3] += xv * wa.w;
        aB[0] += xv * wb.x; aB[1] += xv * wb.y; aB[2] += xv * wb.z; aB[3] += xv * wb.w;
    }
    #pragma unroll
    for (int off = 32; off >= 1; off >>= 1) {
        #pragma unroll
        for (int j = 0; j < 4; ++j) {
            aA[j] += __shfl_xor(aA[j], off);
            aB[j] += __shfl_xor(aB[j], off);
        }
    }
    if (lane == 0) {
        double lA[4], lB[4];
        #pragma unroll
        for (int j = 0; j < 4; ++j) {
            lA[j] = aA[j] + (double)bga[j];
            lB[j] = aB[j] + (double)bgb[j];
        }
        int ia = 0, ib = 0;
        #pragma unroll
        for (int j = 1; j < 4; ++j) {
            if (lA[j] > lA[ia]) ia = j;   // first-max, matches np.argmax
            if (lB[j] > lB[ib]) ib = j;
        }
        double sA = 0., sB = 0., pA[4], pB[4];
        #pragma unroll
        for (int j = 0; j < 4; ++j) {
            pA[j] = exp(lA[j] - lA[ia]); sA += pA[j];
            pB[j] = exp(lB[j] - lB[ib]); sB += pB[j];
        }
        float4 oa, ob;
        oa.x = (float)(pA[0]/sA); oa.y = (float)(pA[1]/sA);
        oa.z = (float)(pA[2]/sA); oa.w = (float)(pA[3]/sA);
        ob.x = (float)(pB[0]/sB); ob.y = (float)(pB[1]/sB);
        ob.z = (float)(pB[2]/sB); ob.w = (float)(pB[3]/sB);
        *(float4*)(probsA + t * 4) = oa;
        *(float4*)(probsB + t * 4) = ob;
        e_idx[t] = ia * 4 + ib;
    }
}

// ------- single-block: sums, counts, padded offsets, aux, slot assignment ----
__global__ __launch_bounds__(256) void moe_stats(
    const float* __restrict__ probsA, const float* __restrict__ probsB,
    const int* __restrict__ e_idx,
    int* __restrict__ countE, int* __restrict__ offsetsP, int* __restrict__ perm,
    float* __restrict__ aux_out)
{
    __shared__ float sA[4], sB[4];
    __shared__ int cA[4], cB[4], cE[16], cur[16], offS[16];
    int tid = threadIdx.x;
    if (tid < 4) { sA[tid] = 0.f; sB[tid] = 0.f; cA[tid] = 0; cB[tid] = 0; }
    if (tid < 16) { cE[tid] = 0; cur[tid] = 0; }
    __syncthreads();
    float lA[4] = {0,0,0,0}, lB[4] = {0,0,0,0};
    for (int t = tid; t < TOKENS; t += 256) {
        float4 pa = *(const float4*)(probsA + t * 4);
        float4 pb = *(const float4*)(probsB + t * 4);
        lA[0] += pa.x; lA[1] += pa.y; lA[2] += pa.z; lA[3] += pa.w;
        lB[0] += pb.x; lB[1] += pb.y; lB[2] += pb.z; lB[3] += pb.w;
        int e = e_idx[t];
        atomicAdd(&cE[e], 1);
        atomicAdd(&cA[e >> 2], 1);
        atomicAdd(&cB[e & 3], 1);
    }
    #pragma unroll
    for (int j = 0; j < 4; ++j) {
        atomicAdd(&sA[j], lA[j]);
        atomicAdd(&sB[j], lB[j]);
    }
    __syncthreads();
    if (tid == 0) {
        int acc = 0;
        for (int e = 0; e < NE; ++e) {
            offS[e] = acc; offsetsP[e] = acc; countE[e] = cE[e];
            acc += (cE[e] + 15) & ~15;          // pad each expert base to 16
        }
        offsetsP[NE] = acc;
        float invT = 1.0f / (float)TOKENS;
        float auxA = 0.f, auxB = 0.f;
        for (int j = 0; j < 4; ++j) {
            auxA += (sA[j] * invT) * ((float)cA[j] * invT);
            auxB += (sB[j] * invT) * ((float)cB[j] * invT);
        }
        aux_out[0] = 4.0f * auxA + 4.0f * auxB;
    }
    __syncthreads();
    for (int s = tid; s < PADROWS; s += 256) perm[s] = 0;   // pad slots -> token 0
    __syncthreads();
    for (int t = tid; t < TOKENS; t += 256) {
        int e = e_idx[t];
        int s = offS[e] + atomicAdd(&cur[e], 1);
        perm[s] = t;
    }
}

// --- gather x rows into MFMA-A-fragment-swizzled bf16 buffer ----------------
// Layout: for 16-row group g, k-chunk c (32 k): 64 "lanes" x 8 bf16, where
// lane = (m&15) + 16*((k>>3)&3), elem j = k&7. One coalesced 16B store/lane.
__global__ __launch_bounds__(256) void moe_gather(const float* __restrict__ x,
                                                  const int* __restrict__ perm,
                                                  unsigned short* __restrict__ Xg2)
{
    int g = blockIdx.x;
    int wv = threadIdx.x >> 6, lane = threadIdx.x & 63;
    int r = lane & 15, ko = (lane >> 4) * 8;
    int t = perm[g * 16 + r];
    const float* xr = x + (size_t)t * DM;
    for (int c = wv; c < DM / 32; c += 4) {
        int k = c * 32 + ko;
        float4 v0 = *(const float4*)(xr + k);
        float4 v1 = *(const float4*)(xr + k + 4);
        BF8 o;
        o.u[0] = f2bf(v0.x); o.u[1] = f2bf(v0.y); o.u[2] = f2bf(v0.z); o.u[3] = f2bf(v0.w);
        o.u[4] = f2bf(v1.x); o.u[5] = f2bf(v1.y); o.u[6] = f2bf(v1.z); o.u[7] = f2bf(v1.w);
        *(bf16x8*)(Xg2 + ((size_t)(g * (DM / 32) + c) * 64 + lane) * 8) = o.v;
    }
}

// ---------------- GEMM1: h = Xg @ W1[e] (+b1), act = a * silu(g) ------------
// grid (DFF/32, NE), block 256 = 4 waves: wn (2) x 16 act-cols, wm (2) x 128
// M-rows. NO LDS, NO barriers: A-frags coalesced from swizzled Xg2, B cols
// direct from global fp32 (converted in-register), prefetch 1 k-step ahead.
__global__ __launch_bounds__(256) void moe_ffn1(
    const unsigned short* __restrict__ Xg2, const float* __restrict__ W1,
    const float* __restrict__ b1, const int* __restrict__ countE,
    const int* __restrict__ offsetsP, unsigned short* __restrict__ actbuf2)
{
    int e = blockIdx.y;
    int cnt = countE[e];
    if (cnt == 0) return;
    int baseP = offsetsP[e];
    int tid = threadIdx.x, wv = tid >> 6, lane = tid & 63;
    int wn = wv & 1, wm = wv >> 1;
    int quad = lane >> 4, l15 = lane & 15;
    int n0 = blockIdx.x * 32;
    int col = n0 + wn * 16 + l15;
    const float* W1e = W1 + (size_t)e * DM * HC;
    const float* pa = W1e + col;
    const float* pg = W1e + DFF + col;
    float ba = b1[e * HC + col];
    float bg = b1[e * HC + DFF + col];
    int colHi = col >> 5, colSw = 16 * ((col >> 3) & 3), colLo = col & 7;

    for (int m0 = wm * 128; m0 < cnt; m0 += 256) {
        int sg0 = (baseP >> 4) + (m0 >> 4);
        floatx4 acc[8][2];
        #pragma unroll
        for (int i = 0; i < 8; ++i) {
            acc[i][0] = floatx4{0.f,0.f,0.f,0.f};
            acc[i][1] = floatx4{0.f,0.f,0.f,0.f};
        }
        float curA[8], curG[8];
        {
            const float* qa = pa + (size_t)(quad * 8) * HC;
            const float* qg = pg + (size_t)(quad * 8) * HC;
            #pragma unroll
            for (int j = 0; j < 8; ++j) { curA[j] = qa[(size_t)j * HC]; curG[j] = qg[(size_t)j * HC]; }
        }
        for (int ks = 0; ks < DM / 32; ++ks) {
            bf16x8 af[8];
            #pragma unroll
            for (int i = 0; i < 8; ++i)
                af[i] = *(const bf16x8*)(Xg2 + ((size_t)((sg0 + i) * (DM / 32) + ks) * 64 + lane) * 8);
            float nxtA[8], nxtG[8];
            if (ks + 1 < DM / 32) {
                const float* qa = pa + (size_t)((ks + 1) * 32 + quad * 8) * HC;
                const float* qg = pg + (size_t)((ks + 1) * 32 + quad * 8) * HC;
                #pragma unroll
                for (int j = 0; j < 8; ++j) { nxtA[j] = qa[(size_t)j * HC]; nxtG[j] = qg[(size_t)j * HC]; }
            }
            BF8 fa, fg;
            #pragma unroll
            for (int j = 0; j < 8; ++j) { fa.u[j] = f2bf(curA[j]); fg.u[j] = f2bf(curG[j]); }
            #pragma unroll
            for (int i = 0; i < 8; ++i) {
                acc[i][0] = __builtin_amdgcn_mfma_f32_16x16x32_bf16(af[i], fa.v, acc[i][0], 0, 0, 0);
                acc[i][1] = __builtin_amdgcn_mfma_f32_16x16x32_bf16(af[i], fg.v, acc[i][1], 0, 0, 0);
            }
            #pragma unroll
            for (int j = 0; j < 8; ++j) { curA[j] = nxtA[j]; curG[j] = nxtG[j]; }
        }
        // epilogue: act = (a+ba)*silu(g+bg), write A-frag-swizzled bf16 (K=DFF)
        #pragma unroll
        for (int i = 0; i < 8; ++i) {
            #pragma unroll
            for (int r = 0; r < 4; ++r) {
                int mr = m0 + i * 16 + quad * 4 + r;
                if (mr < cnt) {
                    float a = acc[i][0][r] + ba;
                    float g = acc[i][1][r] + bg;
                    float sg = 1.0f / (1.0f + __expf(-g));
                    size_t a8 = ((size_t)((sg0 + i) * (DFF / 32) + colHi) * 64
                                 + (quad * 4 + r) + colSw);
                    actbuf2[a8 * 8 + colLo] = f2bf(a * (g * sg));
                }
            }
        }
    }
}

// ---------------- GEMM2: y = act @ W2[e] + b2, scatter rows via perm --------
// grid (DM/32, NE). Same barrier-free structure, K=2048.
__global__ __launch_bounds__(256) void moe_ffn2(
    const unsigned short* __restrict__ actbuf2, const float* __restrict__ W2,
    const float* __restrict__ b2, const int* __restrict__ countE,
    const int* __restrict__ offsetsP, const int* __restrict__ perm,
    float* __restrict__ out)
{
    int e = blockIdx.y;
    int cnt = countE[e];
    if (cnt == 0) return;
    int baseP = offsetsP[e];
    int tid = threadIdx.x, wv = tid >> 6, lane = tid & 63;
    int wn = wv & 1, wm = wv >> 1;
    int quad = lane >> 4, l15 = lane & 15;
    int n0 = blockIdx.x * 32;
    int col = n0 + wn * 16 + l15;
    const float* W2e = W2 + (size_t)e * DFF * DM;
    const float* pb = W2e + col;
    float bias = b2[e * DM + col];

    for (int m0 = wm * 128; m0 < cnt; m0 += 256) {
        int sg0 = (baseP >> 4) + (m0 >> 4);
        floatx4 acc[8];
        #pragma unroll
        for (int i = 0; i < 8; ++i) acc[i] = floatx4{0.f,0.f,0.f,0.f};
        float curB[8];
        {
            const float* qb = pb + (size_t)(quad * 8) * DM;
            #pragma unroll
            for (int j = 0; j < 8; ++j) curB[j] = qb[(size_t)j * DM];
        }
        for (int ks = 0; ks < DFF / 32; ++ks) {
            bf16x8 af[8];
            #pragma unroll
            for (int i = 0; i < 8; ++i)
                af[i] = *(const bf16x8*)(actbuf2 + ((size_t)((sg0 + i) * (DFF / 32) + ks) * 64 + lane) * 8);
            float nxtB[8];
            if (ks + 1 < DFF / 32) {
                const float* qb = pb + (size_t)((ks + 1) * 32 + quad * 8) * DM;
                #pragma unroll
                for (int j = 0; j < 8; ++j) nxtB[j] = qb[(size_t)j * DM];
            }
            BF8 fb;
            #pragma unroll
            for (int j = 0; j < 8; ++j) fb.u[j] = f2bf(curB[j]);
            #pragma unroll
            for (int i = 0; i < 8; ++i)
                acc[i] = __builtin_amdgcn_mfma_f32_16x16x32_bf16(af[i], fb.v, acc[i], 0, 0, 0);
            #pragma unroll
            for (int j = 0; j < 8; ++j) curB[j] = nxtB[j];
        }
        #pragma unroll
        for (int i = 0; i < 8; ++i) {
            #pragma unroll
            for (int r = 0; r < 4; ++r) {
                int mr = m0 + i * 16 + quad * 4 + r;
                if (mr < cnt) {
                    int t = perm[baseP + mr];
                    out[(size_t)t * DM + col] = acc[i][r] + bias;
                }
            }
        }
    }
}

extern "C" void kernel_launch(void* const* d_in, const int* in_sizes, int n_in,
                              void* d_out, int out_size, void* d_ws, size_t ws_size,
                              hipStream_t stream)
{
    (void)in_sizes; (void)n_in; (void)out_size; (void)ws_size;
    const float* x   = (const float*)d_in[0];
    const float* W1  = (const float*)d_in[1];
    const float* b1  = (const float*)d_in[2];
    const float* W2  = (const float*)d_in[3];
    const float* b2  = (const float*)d_in[4];
    const float* Wga = (const float*)d_in[5];
    const float* bga = (const float*)d_in[6];
    const float* Wgb = (const float*)d_in[7];
    const float* bgb = (const float*)d_in[8];
    float* out = (float*)d_out;

    // ws layout (16 MiB):
    //   0       countE[16]        64      offsetsP[17]
    //   256     e_idx[2048]       16384   probsA[8192]f   49152 probsB[8192]f
    //   81920   perm[2560]
    //   1 MiB   Xg2  bf16 swizzled [2560 rows x 1024]  (5 MiB)
    //   6 MiB   actbuf2 bf16 swizzled [2560 rows x 2048] (10 MiB)
    char* ws = (char*)d_ws;
    int*   countE   = (int*)(ws + 0);
    int*   offsetsP = (int*)(ws + 64);
    int*   e_idx    = (int*)(ws + 256);
    float* probsA   = (float*)(ws + 16384);
    float* probsB   = (float*)(ws + 49152);
    int*   perm     = (int*)(ws + 81920);
    unsigned short* Xg2     = (unsigned short*)(ws + (size_t)1 * 1024 * 1024);
    unsigned short* actbuf2 = (unsigned short*)(ws + (size_t)6 * 1024 * 1024);

    moe_gating<<<TOKENS / 4, 256, 0, stream>>>(x, Wga, bga, Wgb, bgb,
                                               probsA, probsB, e_idx);
    moe_stats<<<1, 256, 0, stream>>>(probsA, probsB, e_idx, countE, offsetsP, perm,
                                     out + (size_t)TOKENS * DM);
    moe_gather<<<PADROWS / 16, 256, 0, stream>>>(x, perm, Xg2);
    moe_ffn1<<<dim3(DFF / 32, NE), 256, 0, stream>>>(Xg2, W1, b1, countE, offsetsP, actbuf2);
    moe_ffn2<<<dim3(DM / 32, NE), 256, 0, stream>>>(actbuf2, W2, b2, countE, offsetsP, perm, out);
}